// Round 8
// baseline (799.538 us; speedup 1.0000x reference)
//
#include <hip/hip_runtime.h>
#include <hip/hip_bf16.h>
#include <hip/hip_fp16.h>
#include <cstdint>
#include <cstddef>

// Problem constants
#define B_ROWS 32768
#define DIM    256
#define NBLK64 128          // 64-wide column blocks per row (8192/64)
#define CERT_M 3.0e-3f      // >= 2*eps_f16 (2.2e-3) + 2*key-trunc (6e-4)
#define PRE_M  3.0e-3f      // >= eps_f16 + prescan eps + trunc

typedef _Float16 f16x8  __attribute__((ext_vector_type(8)));
typedef float    f32x16 __attribute__((ext_vector_type(16)));
typedef unsigned short u16x8 __attribute__((ext_vector_type(8)));

// ---- workspace layout (bytes) ----
#define WS_XBF     ((size_t)0)                    // 32768*256*2 = 16 MB (f16 normalized x)
#define WS_CBBF    ((size_t)16777216)             //  8192*256*2 =  4 MB (f16 normalized cb)
#define WS_TOPINFO ((size_t)20971520)             // 32768*128*8 = 32 MB {u32 k1, u32 k2}
#define WS_CNORM   ((size_t)54525952)             //  8192*8     = 64 KB (fp64 inverse norms)
#define WS_QUEUE   ((size_t)54591488)             // 32768*4     = 128 KB (uncertified rows)
#define WS_LOSS    ((size_t)54722560)             // 4 B
#define WS_QCNT    ((size_t)54722568)             // 4 B

// ---- output layout (floats, concatenated in return order) ----
#define OUT_XQ   ((size_t)0)
#define OUT_LOSS ((size_t)8388608)
#define OUT_IDX  ((size_t)8388609)
#define OUT_SCAL ((size_t)(8388609 + 32768))

__device__ inline double wave_sum_d(double v){ for (int d = 1; d < 64; d <<= 1) v += __shfl_xor(v, d); return v; }
__device__ inline unsigned umax_(unsigned a, unsigned b){ return a > b ? a : b; }

// order-preserving f32 bit keys (no NaNs in this data)
__device__ inline unsigned okey(float f){
    unsigned u = __float_as_uint(f);
    return ((int)u < 0) ? ~u : (u | 0x80000000u);
}
__device__ inline float kinv(unsigned k){
    unsigned u = (k & 0x80000000u) ? (k & 0x7FFFFFFFu) : ~k;
    return __uint_as_float(u);
}

// NOTE: the builtin's size/offset operands must be compile-time constants —
// fold any variable offset into the pointer, keep imm offset = 0 (R7 lesson).
__device__ inline void load16_lds(const void* g, void* l) {
    __builtin_amdgcn_global_load_lds(
        (const __attribute__((address_space(1))) unsigned int*)g,
        (__attribute__((address_space(3))) unsigned int*)l, 16, 0, 0);
}

// shared finalize: scalar/proj/x_q/commit for one row (whole wave)
__device__ inline void finalize_row(const float* __restrict__ x, const float* __restrict__ cb,
                                    int row, int best_i, int lane,
                                    float* __restrict__ out, float* __restrict__ loss_acc,
                                    float4 xv) {
    float4 cv = ((const float4*)(cb + (size_t)best_i * DIM))[lane];
    float dot = xv.x * cv.x + xv.y * cv.y + xv.z * cv.z + xv.w * cv.w;
    float nsq = cv.x * cv.x + cv.y * cv.y + cv.z * cv.z + cv.w * cv.w;
    float xsq = xv.x * xv.x + xv.y * xv.y + xv.z * xv.z + xv.w * xv.w;
    for (int d = 1; d < 64; d <<= 1) {
        dot += __shfl_xor(dot, d);
        nsq += __shfl_xor(nsq, d);
        xsq += __shfl_xor(xsq, d);
    }
    float scalar = dot / (nsq + 1e-8f);
    float4 pj = {scalar * cv.x, scalar * cv.y, scalar * cv.z, scalar * cv.w};
    ((float4*)(out + OUT_XQ + (size_t)row * DIM))[lane] = pj;
    float pn = fmaxf(sqrtf(scalar * scalar * nsq), 1e-8f);
    float xn = fmaxf(sqrtf(xsq), 1e-8f);
    float commit = (scalar * dot) / (pn * xn);
    if (lane == 0) {
        out[OUT_IDX + row]  = (float)best_i;
        out[OUT_SCAL + row] = scalar;
        atomicAdd(loss_acc, 1.f - commit);
    }
}

// ---------------------------------------------------------------------------
// Phase 0: per-row L2 norms, f16 (RNE) normalized copies, fp64 inverse norms.
// ---------------------------------------------------------------------------
__global__ __launch_bounds__(256)
void prep_kernel(const float* __restrict__ x, const float* __restrict__ cb,
                 ushort* __restrict__ xbf, ushort* __restrict__ cbbf,
                 double* __restrict__ inv_cnorm, float* __restrict__ loss_acc,
                 int* __restrict__ qcount) {
    if (blockIdx.x == 0 && threadIdx.x == 0) { *loss_acc = 0.f; *qcount = 0; }
    int gw   = blockIdx.x * 4 + (threadIdx.x >> 6);
    int lane = threadIdx.x & 63;
    bool is_cb = gw >= B_ROWS;
    int row  = is_cb ? gw - B_ROWS : gw;
    const float* src = is_cb ? cb + (size_t)row * DIM : x + (size_t)row * DIM;
    ushort*      dst = is_cb ? cbbf + (size_t)row * DIM : xbf + (size_t)row * DIM;

    float4 v = ((const float4*)src)[lane];
    double ss = (double)v.x * v.x + (double)v.y * v.y + (double)v.z * v.z + (double)v.w * v.w;
    ss = wave_sum_d(ss);
    float inv = 1.f / fmaxf(sqrtf((float)ss), 1e-12f);
    ushort4 o;
    o.x = __half_as_ushort(__float2half(v.x * inv));
    o.y = __half_as_ushort(__float2half(v.y * inv));
    o.z = __half_as_ushort(__float2half(v.z * inv));
    o.w = __half_as_ushort(__float2half(v.w * inv));
    ((ushort4*)dst)[lane] = o;
    if (is_cb && lane == 0) inv_cnorm[row] = 1.0 / sqrt(ss);
}

// ---------------------------------------------------------------------------
// Phase 1: f16 MFMA filter, 32x32x16 TRANSPOSED. mfma(cb_frag, x_frag):
// D "col" = lane&31 = x row (fixed per lane); 16 in-lane values per tile =
// cb cols (reg&3)+8*(reg>>2)+4*(lane>>5). Per-row top1/top2 over each 64-col
// block = in-lane 32-key incremental top2 + ONE shfl_xor(32) merge.
// XOR-swizzled LDS (chunk p of row r holds global chunk p^(r&7)).
// ---------------------------------------------------------------------------
__global__ __launch_bounds__(256, 2)
void simmax_kernel(const ushort* __restrict__ xbf, const ushort* __restrict__ cbbf,
                   uint2* __restrict__ topinfo) {
    __shared__ __align__(16) ushort As[128 * 64];
    __shared__ __align__(16) ushort Bs[128 * 64];
    const int t   = threadIdx.x;
    const int rm0 = blockIdx.x * 128;          // row-tile   (x rows)
    const int by  = blockIdx.y;
    const int cn0 = by * 128;                  // col-tile   (codebook rows)
    const int wid = t >> 6, lane = t & 63;
    const int wy = wid >> 1, wx = wid & 1;
    const int m32 = lane & 31, h = lane >> 5;

    f32x16 acc[2][2];   // [it = cb 32-tile][jt = x 32-tile]
#pragma unroll
    for (int i = 0; i < 2; i++)
#pragma unroll
        for (int j = 0; j < 2; j++)
#pragma unroll
            for (int r = 0; r < 16; r++) acc[i][j][r] = 0.f;

    const int srow     = t >> 3;
    const int cpos     = t & 7;
    const int scol_src = (cpos ^ (srow & 7)) * 8;
    const int scol_lds = cpos * 8;

#pragma unroll
    for (int ks = 0; ks < 4; ++ks) {
        const int k0 = ks * 64;
#pragma unroll
        for (int it = 0; it < 4; ++it) {
            const int row = it * 32 + srow;
            const int ldsoff = row * 64 + scol_lds;
            load16_lds(xbf  + (size_t)(rm0 + row) * DIM + k0 + scol_src, As + ldsoff);
            load16_lds(cbbf + (size_t)(cn0 + row) * DIM + k0 + scol_src, Bs + ldsoff);
        }
        __syncthreads();
#pragma unroll
        for (int kt = 0; kt < 4; ++kt) {            // K-step of 16 within BK=64
            const int cs = ((kt * 2 + h) ^ (m32 & 7)) * 8;
            f16x8 xa[2], cba[2];
#pragma unroll
            for (int jt = 0; jt < 2; ++jt)
                xa[jt] = *(const f16x8*)(As + (wy * 64 + jt * 32 + m32) * 64 + cs);
#pragma unroll
            for (int it = 0; it < 2; ++it)
                cba[it] = *(const f16x8*)(Bs + (wx * 64 + it * 32 + m32) * 64 + cs);
#pragma unroll
            for (int it = 0; it < 2; ++it)
#pragma unroll
                for (int jt = 0; jt < 2; ++jt)
                    acc[it][jt] = __builtin_amdgcn_mfma_f32_32x32x16_f16(
                        cba[it], xa[jt], acc[it][jt], 0, 0, 0);   // TRANSPOSED
        }
        __syncthreads();
    }

    // Epilogue: per jt, this lane's x row = rm0 + wy*64 + jt*32 + m32.
    const int blockglob = by * 2 + wx;
    const unsigned ib = 8191 - (unsigned)(cn0 + wx * 64 + 4 * h);
#pragma unroll
    for (int jt = 0; jt < 2; ++jt) {
        unsigned m1 = 0, m2 = 0;
#pragma unroll
        for (int it = 0; it < 2; ++it)
#pragma unroll
            for (int reg = 0; reg < 16; ++reg) {
                unsigned key = (okey(acc[it][jt][reg]) & 0xFFFFE000u)
                             | (ib - (unsigned)(it * 32 + (reg & 3) + 8 * (reg >> 2)));
                bool gt = key > m1;
                m2 = gt ? m1 : umax_(m2, key);
                m1 = gt ? key : m1;
            }
        unsigned o1 = (unsigned)__shfl_xor((int)m1, 32);
        unsigned o2 = (unsigned)__shfl_xor((int)m2, 32);
        unsigned lo = m1 < o1 ? m1 : o1;
        m2 = umax_(umax_(m2, o2), lo);
        m1 = umax_(m1, o1);
        if (h == 0) {
            int rowg = rm0 + wy * 64 + jt * 32 + m32;
            topinfo[(size_t)rowg * NBLK64 + blockglob] = make_uint2(m1, m2);
        }
    }
}

// ---------------------------------------------------------------------------
// Phase 2a: cert kernel. One wave per row; reads 1 KB of topinfo; certified
// rows (gap > CERT_M) are finalized inline with zero gather; uncertified rows
// go to the queue for the fallback kernel.
// ---------------------------------------------------------------------------
__global__ __launch_bounds__(256)
void cert_kernel(const float* __restrict__ x, const float* __restrict__ cb,
                 const uint2* __restrict__ topinfo,
                 float* __restrict__ out, float* __restrict__ loss_acc,
                 int* __restrict__ queue, int* __restrict__ qcount) {
    const int row  = blockIdx.x * 4 + (threadIdx.x >> 6);
    const int lane = threadIdx.x & 63;

    uint4 tt = ((const uint4*)(topinfo + (size_t)row * NBLK64))[lane];
    unsigned k1[2] = {tt.x, tt.z};
    unsigned k2[2] = {tt.y, tt.w};

    unsigned W = umax_(k1[0], k1[1]);
    for (int d = 1; d < 64; d <<= 1) W = umax_(W, (unsigned)__shfl_xor((int)W, d));
    unsigned R = umax_((k1[0] == W) ? k2[0] : k1[0], (k1[1] == W) ? k2[1] : k1[1]);
    for (int d = 1; d < 64; d <<= 1) R = umax_(R, (unsigned)__shfl_xor((int)R, d));

    float v1w = kinv(W & 0xFFFFE000u);
    float rvf = kinv(R & 0xFFFFE000u);

    if (v1w - rvf > CERT_M) {                 // wave-uniform
        int best_i = 8191 - (int)(W & 0x1FFFu);
        float4 xv = ((const float4*)(x + (size_t)row * DIM))[lane];
        finalize_row(x, cb, row, best_i, lane, out, loss_acc, xv);
    } else if (lane == 0) {
        int s = atomicAdd(qcount, 1);
        queue[s] = row;
    }
}

// ---------------------------------------------------------------------------
// Phase 2b: fallback kernel — only queued rows (~18%). f32 prescan from
// L2-resident f16 codebook, exact fp64 eval of survivors from fp32 data
// (same formula/tiebreak as R2-R6), then finalize.
// ---------------------------------------------------------------------------
__global__ __launch_bounds__(256)
void fb_kernel(const float* __restrict__ x, const float* __restrict__ cb,
               const ushort* __restrict__ xbf, const ushort* __restrict__ cbbf,
               const uint2* __restrict__ topinfo, const double* __restrict__ inv_cnorm,
               const int* __restrict__ queue, const int* __restrict__ qcount,
               float* __restrict__ out, float* __restrict__ loss_acc) {
    const int g = blockIdx.x * 4 + (threadIdx.x >> 6);
    if (g >= *qcount) return;
    const int row  = queue[g];
    const int lane = threadIdx.x & 63;

    uint4 tt = ((const uint4*)(topinfo + (size_t)row * NBLK64))[lane];
    unsigned k1[2] = {tt.x, tt.z};
    unsigned W = umax_(k1[0], k1[1]);
    for (int d = 1; d < 64; d <<= 1) W = umax_(W, (unsigned)__shfl_xor((int)W, d));
    float v1w = kinv(W & 0xFFFFE000u);

    float4 xv = ((const float4*)(x + (size_t)row * DIM))[lane];

    const int c = lane >> 3, e = lane & 7;
    float xh[32];
#pragma unroll
    for (int k4 = 0; k4 < 4; ++k4) {
        u16x8 hx = ((const u16x8*)(xbf + (size_t)row * DIM + e * 32))[k4];
#pragma unroll
        for (int j = 0; j < 8; ++j)
            xh[k4 * 8 + j] = __half2float(__ushort_as_half((ushort)hx[j]));
    }

    double best_s = -1e300;
    int bi = 0x7fffffff;
    auto exact_eval = [&](int n) {
        float4 cv = ((const float4*)(cb + (size_t)n * DIM))[lane];
        double s = (double)xv.x * cv.x + (double)xv.y * cv.y +
                   (double)xv.z * cv.z + (double)xv.w * cv.w;
        s = wave_sum_d(s);
        s *= inv_cnorm[n];
        if (s > best_s || (s == best_s && n < bi)) { best_s = s; bi = n; }
    };

    const float thrblk = v1w - CERT_M;
    const float thrpre = v1w - PRE_M;
    float v1f[2] = {kinv(k1[0] & 0xFFFFE000u), kinv(k1[1] & 0xFFFFE000u)};
#pragma unroll
    for (int s = 0; s < 2; ++s) {
        unsigned long long bm = __ballot(v1f[s] >= thrblk);   // wave-uniform
        while (bm) {
            int src = __ffsll((unsigned long long)bm) - 1;
            bm &= bm - 1;
            int blk = src * 2 + s;
#pragma unroll 1
            for (int sub = 0; sub < 8; ++sub) {
                int n = blk * 64 + sub * 8 + c;
                float s0 = 0.f, s1 = 0.f, s2 = 0.f, s3 = 0.f;
#pragma unroll
                for (int k4 = 0; k4 < 4; ++k4) {
                    u16x8 chv = ((const u16x8*)(cbbf + (size_t)n * DIM + e * 32))[k4];
#pragma unroll
                    for (int j = 0; j < 8; ++j) {
                        float cf = __half2float(__ushort_as_half((ushort)chv[j]));
                        float xf = xh[k4 * 8 + j];
                        if ((j & 3) == 0) s0 = fmaf(xf, cf, s0);
                        else if ((j & 3) == 1) s1 = fmaf(xf, cf, s1);
                        else if ((j & 3) == 2) s2 = fmaf(xf, cf, s2);
                        else s3 = fmaf(xf, cf, s3);
                    }
                }
                float ps = (s0 + s1) + (s2 + s3);
                ps += __shfl_xor(ps, 1);
                ps += __shfl_xor(ps, 2);
                ps += __shfl_xor(ps, 4);
                unsigned long long sv = __ballot(e == 0 && ps >= thrpre);
                while (sv) {
                    int b = __ffsll((unsigned long long)sv) - 1;
                    sv &= sv - 1;
                    exact_eval(blk * 64 + sub * 8 + (b >> 3));
                }
            }
        }
    }
    for (int d = 1; d < 64; d <<= 1) {
        double os = __shfl_xor(best_s, d);
        int    oi = __shfl_xor(bi, d);
        if (os > best_s || (os == best_s && oi < bi)) { best_s = os; bi = oi; }
    }
    finalize_row(x, cb, row, bi, lane, out, loss_acc, xv);
}

__global__ void loss_kernel(const float* __restrict__ loss_acc, float* __restrict__ out) {
    out[OUT_LOSS] = 0.25f * (*loss_acc) * (1.0f / 32768.0f);
}

// ---------------------------------------------------------------------------
extern "C" void kernel_launch(void* const* d_in, const int* in_sizes, int n_in,
                              void* d_out, int out_size, void* d_ws, size_t ws_size,
                              hipStream_t stream) {
    const float* x  = (const float*)d_in[0];
    const float* cb = (const float*)d_in[1];
    float* out = (float*)d_out;
    char*  ws  = (char*)d_ws;
    ushort* xbf    = (ushort*)(ws + WS_XBF);
    ushort* cbbf   = (ushort*)(ws + WS_CBBF);
    uint2*  topinfo = (uint2*)(ws + WS_TOPINFO);
    double* inv_cn = (double*)(ws + WS_CNORM);
    int*    queue  = (int*)(ws + WS_QUEUE);
    float*  loss_acc = (float*)(ws + WS_LOSS);
    int*    qcount = (int*)(ws + WS_QCNT);

    hipLaunchKernelGGL(prep_kernel, dim3((B_ROWS + 8192) / 4), dim3(256), 0, stream,
                       x, cb, xbf, cbbf, inv_cn, loss_acc, qcount);
    hipLaunchKernelGGL(simmax_kernel, dim3(B_ROWS / 128, 8192 / 128), dim3(256), 0, stream,
                       xbf, cbbf, topinfo);
    hipLaunchKernelGGL(cert_kernel, dim3(B_ROWS / 4), dim3(256), 0, stream,
                       x, cb, topinfo, out, loss_acc, queue, qcount);
    hipLaunchKernelGGL(fb_kernel, dim3(B_ROWS / 4), dim3(256), 0, stream,
                       x, cb, xbf, cbbf, topinfo, inv_cn, queue, qcount, out, loss_acc);
    hipLaunchKernelGGL(loss_kernel, dim3(1), dim3(1), 0, stream, loss_acc, out);
}